// Round 2
// baseline (552.746 us; speedup 1.0000x reference)
//
#include <hip/hip_runtime.h>

#define H 256
#define W 256
#define CIN 16
#define COUT 16
#define OH 254
#define OW 254
#define HW (H * W)

typedef int int4v __attribute__((ext_vector_type(4)));
typedef int int2v __attribute__((ext_vector_type(2)));

// pack low bytes of 4 dwords -> 1 dword: [d0.b0, d1.b0, d2.b0, d3.b0]
static __device__ __forceinline__ int pack4(int d0, int d1, int d2, int d3) {
    int t0 = __builtin_amdgcn_perm(d1, d0, 0x00000400);  // [d0.b0, d1.b0, x, x]
    int t1 = __builtin_amdgcn_perm(d3, d2, 0x00000400);  // [d2.b0, d3.b0, x, x]
    return __builtin_amdgcn_perm(t1, t0, 0x05040100);
}

// ============================================================================
// Kernel 1: pack int32 NCHW -> int8-packed NHWC16 (16 B per pixel) into d_ws.
// Pure streaming transpose-gather: 268 MB read + 67 MB write. 2 pixels/thread.
// ============================================================================
__global__ __launch_bounds__(256) void pack_x(
    const int* __restrict__ x, int4v* __restrict__ xpk)
{
    const int t  = blockIdx.x * 256 + threadIdx.x;   // [0, 64*65536/2)
    const int p2 = t * 2;                            // even pixel index
    const int n   = p2 >> 16;
    const int pix = p2 & 65535;
    const int* p = x + (size_t)n * (CIN * HW) + pix;
    int4v pk0, pk1;
#pragma unroll
    for (int q = 0; q < 4; ++q) {
        const int2v d0 = *(const int2v*)(p + (q * 4 + 0) * HW);
        const int2v d1 = *(const int2v*)(p + (q * 4 + 1) * HW);
        const int2v d2 = *(const int2v*)(p + (q * 4 + 2) * HW);
        const int2v d3 = *(const int2v*)(p + (q * 4 + 3) * HW);
        pk0[q] = pack4(d0.x, d1.x, d2.x, d3.x);
        pk1[q] = pack4(d0.y, d1.y, d2.y, d3.y);
    }
    xpk[p2]     = pk0;
    xpk[p2 + 1] = pk1;
}

// ============================================================================
// Kernel 2: conv reading packed pixels straight from global (L3-resident,
// 67 MB). No input LDS, no stage/compute barrier. Each wave owns one
// (n, ow-group g, 32-row oh chunk) job and rolls 3 B-fragments + 3 row-sums
// over oh: per output row = 1 global dwordx4 load + 4 MFMAs + 4 stores.
// out[n][co][oh][ow] = 1e-4*(Sum x*w - 3*Sum(x) - 7*Sum(w) + 3024) + bdeq[co]
// A-lane: m=lane&15 (co), k-chunk=lane>>4 (kw; kw==3 zero). B-lane: n=lane&15
// (ow off), k-chunk=quad -> pixel col g*16+(lane&15)+quad. C/D: col=lane&15,
// row=quad*4+reg. Out-of-row B cols only feed masked outputs or kw==3 zeros.
// ============================================================================
__global__ __launch_bounds__(256, 6) void conv_q8_stream(
    const int4v* __restrict__ xpk, const int* __restrict__ wq,
    const float* __restrict__ bias, float* __restrict__ out)
{
    __shared__ int4v lds_wA[192];   // [(kh*4 + kw)*16 + co]
    __shared__ int   lds_ci[COUT];  // -7*sumW + 3024
    __shared__ float lds_bf[COUT];  // dequantized bias

    const int tid = threadIdx.x;

    // ---- stage packed A (weights) ----
    if (tid < 192) {
        const int co = tid & 15;
        const int kw = (tid >> 4) & 3;
        const int kh = tid >> 6;
        int4v pk = {0, 0, 0, 0};
        if (kw < 3) {
#pragma unroll
            for (int q = 0; q < 4; ++q) {
                const int* wp = wq + ((co * CIN + q * 4) * 3 + kh) * 3 + kw;
                pk[q] = pack4(wp[0], wp[9], wp[18], wp[27]);
            }
        }
        lds_wA[tid] = pk;
    }
    if (tid < COUT) {
        int s = 0;
        const int* wc = wq + tid * CIN * 9;
#pragma unroll
        for (int k = 0; k < CIN * 9; ++k) s += wc[k];
        lds_ci[tid] = -7 * s + 144 * 21;
        float r = rintf(bias[tid] * 10000.0f);                // round-half-even
        r = fminf(fmaxf(r, -2147483648.0f), 2147483647.0f);   // clamp int32 range
        lds_bf[tid] = r * 1e-4f;
    }
    __syncthreads();

    const int wave = tid >> 6;
    const int lane = tid & 63;
    const int n16  = lane & 15;
    const int quad = lane >> 4;

    const int4v a0 = lds_wA[(0 * 4 + quad) * 16 + n16];
    const int4v a1 = lds_wA[(1 * 4 + quad) * 16 + n16];
    const int4v a2 = lds_wA[(2 * 4 + quad) * 16 + n16];
    const int ov = (quad < 3) ? 0x01010101 : 0;
    const int4v aones = {ov, ov, ov, ov};

    int   ci_r[4];
    float bf_r[4];
#pragma unroll
    for (int r = 0; r < 4; ++r) {
        ci_r[r] = lds_ci[quad * 4 + r];
        bf_r[r] = lds_bf[quad * 4 + r];
    }

    // job decode: job = n*128 + chunk*16 + g  (consecutive waves share rows)
    const int job   = blockIdx.x * 4 + wave;
    const int n     = job >> 7;
    const int rem   = job & 127;
    const int g     = rem & 15;
    const int chunk = rem >> 4;
    const int oh0   = chunk * 32;
    const int ohE   = (oh0 + 32 < OH) ? oh0 + 32 : OH;

    const int col = g * 16 + n16 + quad;          // B pixel column (may overrun row: masked)
    const int4v* xb = xpk + (size_t)n * HW + col; // pixel units
    float* outn = out + (size_t)n * (COUT * OH * OW);
    const int  ow    = g * 16 + n16;
    const bool wmask = ow < OW;

    const int4v zero = {0, 0, 0, 0};
    int4v b0 = xb[(oh0 + 0) * W];
    int4v b1 = xb[(oh0 + 1) * W];
    int ps0 = __builtin_amdgcn_mfma_i32_16x16x64_i8(aones, b0, zero, 0, 0, 0)[0];
    int ps1 = __builtin_amdgcn_mfma_i32_16x16x64_i8(aones, b1, zero, 0, 0, 0)[0];

#pragma unroll 2
    for (int oh = oh0; oh < ohE; ++oh) {
        const int4v b2 = xb[(oh + 2) * W];
        int4v acc = zero;
        acc = __builtin_amdgcn_mfma_i32_16x16x64_i8(a0, b0, acc, 0, 0, 0);
        acc = __builtin_amdgcn_mfma_i32_16x16x64_i8(a1, b1, acc, 0, 0, 0);
        acc = __builtin_amdgcn_mfma_i32_16x16x64_i8(a2, b2, acc, 0, 0, 0);
        const int ps2 = __builtin_amdgcn_mfma_i32_16x16x64_i8(aones, b2, zero, 0, 0, 0)[0];
        const int sx = ps0 + ps1 + ps2;
        if (wmask) {
#pragma unroll
            for (int r = 0; r < 4; ++r) {
                const int co  = quad * 4 + r;
                const int tot = acc[r] - 3 * sx + ci_r[r];
                outn[(co * OH + oh) * OW + ow] = fmaf(1e-4f, (float)tot, bf_r[r]);
            }
        }
        b0 = b1; b1 = b2;
        ps0 = ps1; ps1 = ps2;
    }
}

// ============================================================================
// Fallback: previous fused single-kernel version (used if ws too small).
// ============================================================================
#define OHB 12
#define IRB (OHB + 2)
#define COLS 259
#define NOHG 22
#define NTHREADS 512
#define TILES (OHB * 16)
#define TPW (TILES / 8)

__global__ __launch_bounds__(NTHREADS, 4) void conv_q8_mfma(
    const int* __restrict__ x, const int* __restrict__ wq,
    const float* __restrict__ bias, float* __restrict__ out)
{
    __shared__ int4v lds_x[IRB * COLS];
    __shared__ int4v lds_wA[192];
    __shared__ int   lds_ci[COUT];
    __shared__ float lds_bf[COUT];

    const int tid = threadIdx.x;
    const int ohg = blockIdx.x;
    const int n   = blockIdx.y;
    const int oh0 = ohg * OHB;

    if (tid < 192) {
        const int t = tid;
        const int co = t & 15;
        const int kw = (t >> 4) & 3;
        const int kh = t >> 6;
        int4v pk = {0, 0, 0, 0};
        if (kw < 3) {
#pragma unroll
            for (int q = 0; q < 4; ++q) {
                const int* wp = wq + ((co * CIN + q * 4) * 3 + kh) * 3 + kw;
                pk[q] = pack4(wp[0], wp[9], wp[18], wp[27]);
            }
        }
        lds_wA[t] = pk;
    }
    if (tid < COUT) {
        int s = 0;
        const int* wc = wq + tid * CIN * 9;
#pragma unroll
        for (int k = 0; k < CIN * 9; ++k) s += wc[k];
        lds_ci[tid] = -7 * s + 144 * 21;
        float r = rintf(bias[tid] * 10000.0f);
        r = fminf(fmaxf(r, -2147483648.0f), 2147483647.0f);
        lds_bf[tid] = r * 1e-4f;
    }
    if (tid < IRB * 4) {
        const int row = tid >> 2;
        const int colz = 256 + (tid & 3);
        if (colz < COLS) lds_x[row * COLS + colz] = (int4v){0, 0, 0, 0};
    }

    const int* xn = x + (size_t)n * (CIN * HW);
    for (int t = tid; t < IRB * 128; t += NTHREADS) {
        const int row = t >> 7;
        const int c2 = (t & 127) * 2;
        int ih = oh0 + row;
        if (ih > H - 1) ih = H - 1;
        const int* p = xn + ih * W + c2;
        int4v pk0, pk1;
#pragma unroll
        for (int q = 0; q < 4; ++q) {
            const int2v d0 = *(const int2v*)(p + (q * 4 + 0) * HW);
            const int2v d1 = *(const int2v*)(p + (q * 4 + 1) * HW);
            const int2v d2 = *(const int2v*)(p + (q * 4 + 2) * HW);
            const int2v d3 = *(const int2v*)(p + (q * 4 + 3) * HW);
            pk0[q] = pack4(d0.x, d1.x, d2.x, d3.x);
            pk1[q] = pack4(d0.y, d1.y, d2.y, d3.y);
        }
        lds_x[row * COLS + c2]     = pk0;
        lds_x[row * COLS + c2 + 1] = pk1;
    }
    __syncthreads();

    const int wave = tid >> 6;
    const int lane = tid & 63;
    const int n16  = lane & 15;
    const int quad = lane >> 4;

    const int4v a0 = lds_wA[(0 * 4 + quad) * 16 + n16];
    const int4v a1 = lds_wA[(1 * 4 + quad) * 16 + n16];
    const int4v a2 = lds_wA[(2 * 4 + quad) * 16 + n16];
    const int ov = (quad < 3) ? 0x01010101 : 0;
    const int4v aones = {ov, ov, ov, ov};

    int   ci_r[4];
    float bf_r[4];
#pragma unroll
    for (int r = 0; r < 4; ++r) {
        ci_r[r] = lds_ci[quad * 4 + r];
        bf_r[r] = lds_bf[quad * 4 + r];
    }

    float* outn = out + (size_t)n * (COUT * OH * OW);
    const int coff = n16 + quad;

    for (int t = wave * TPW; t < wave * TPW + TPW; ++t) {
        const int rl = t >> 4;
        const int g  = t & 15;
        const int oh = oh0 + rl;
        if (oh >= OH) continue;
        const int ow0 = g * 16;
        const int c = ow0 + coff;
        const int4v b0 = lds_x[(rl + 0) * COLS + c];
        const int4v b1 = lds_x[(rl + 1) * COLS + c];
        const int4v b2 = lds_x[(rl + 2) * COLS + c];
        int4v acc = {0, 0, 0, 0};
        int4v acs = {0, 0, 0, 0};
        acc = __builtin_amdgcn_mfma_i32_16x16x64_i8(a0, b0, acc, 0, 0, 0);
        acc = __builtin_amdgcn_mfma_i32_16x16x64_i8(a1, b1, acc, 0, 0, 0);
        acc = __builtin_amdgcn_mfma_i32_16x16x64_i8(a2, b2, acc, 0, 0, 0);
        acs = __builtin_amdgcn_mfma_i32_16x16x64_i8(aones, b0, acs, 0, 0, 0);
        acs = __builtin_amdgcn_mfma_i32_16x16x64_i8(aones, b1, acs, 0, 0, 0);
        acs = __builtin_amdgcn_mfma_i32_16x16x64_i8(aones, b2, acs, 0, 0, 0);
        const int sx = acs[0];
        const int ow = ow0 + n16;
        if (ow < OW) {
#pragma unroll
            for (int r = 0; r < 4; ++r) {
                const int co  = quad * 4 + r;
                const int tot = acc[r] - 3 * sx + ci_r[r];
                outn[(co * OH + oh) * OW + ow] = fmaf(1e-4f, (float)tot, bf_r[r]);
            }
        }
    }
}

extern "C" void kernel_launch(void* const* d_in, const int* in_sizes, int n_in,
                              void* d_out, int out_size, void* d_ws, size_t ws_size,
                              hipStream_t stream) {
    const int*   x    = (const int*)d_in[0];
    const int*   wq   = (const int*)d_in[1];
    const float* bias = (const float*)d_in[2];
    float*       out  = (float*)d_out;

    const int n = in_sizes[0] / (CIN * H * W);   // 64
    const size_t ws_needed = (size_t)n * HW * 16 + 1024;  // packed pixels + overrun pad

    if (d_ws != nullptr && ws_size >= ws_needed) {
        int4v* xpk = (int4v*)d_ws;
        // pack: 2 pixels/thread
        const int npix = n * HW;
        pack_x<<<npix / 512, 256, 0, stream>>>(x, xpk);
        // conv: 8 chunks of 32 oh-rows, 16 ow-groups, 4 waves/block
        const int jobs = n * 16 * 8;
        conv_q8_stream<<<jobs / 4, 256, 0, stream>>>(xpk, wq, bias, out);
    } else {
        dim3 grid(NOHG, n);
        conv_q8_mfma<<<grid, NTHREADS, 0, stream>>>(x, wq, bias, out);
    }
}

// Round 3
// 477.538 us; speedup vs baseline: 1.1575x; 1.1575x over previous
//
#include <hip/hip_runtime.h>

#define H 256
#define W 256
#define CIN 16
#define COUT 16
#define OH 254
#define OW 254
#define HW (H * W)

#define OHB 4            // output rows computed per pipeline step
#define RING 10          // LDS ring rows (>= 2*OHB + 2)
#define COLS 259         // cols 0..255 data + 256..258 zero halo (quad overhang)
#define OHC 32           // oh rows per block
#define SPLIT 8          // chunks per image (8*32 = 256 >= 254)
#define STEPS (OHC / OHB)
#define NTHREADS 512

typedef int int4v __attribute__((ext_vector_type(4)));
typedef int int2v __attribute__((ext_vector_type(2)));
typedef float f2v  __attribute__((ext_vector_type(2)));

// pack low bytes of 4 dwords -> 1 dword: [d0.b0, d1.b0, d2.b0, d3.b0]
static __device__ __forceinline__ int pack4(int d0, int d1, int d2, int d3) {
    int t0 = __builtin_amdgcn_perm(d1, d0, 0x00000400);
    int t1 = __builtin_amdgcn_perm(d3, d2, 0x00000400);
    return __builtin_amdgcn_perm(t1, t0, 0x05040100);
}

// out[n][co][oh][ow] = 1e-4*(Sum x*w - 3*Sum(x) - 7*Sum(w) + 3024) + bdeq[co]
//
// Ring-pipelined implicit GEMM, operands SWAPPED vs earlier rounds:
//   A = pixels:  m = lane&15 -> ow offset, k-chunk = lane>>4 = kw (kw==3 dummy),
//                bytes = cin -> pixel col g*16 + (lane&15) + quad.
//   B = weights: n = lane&15 -> co, k-chunk = quad = kw, bytes = cin.
//   D: col = lane&15 = co, row = quad*4+r = ow offset -> each lane holds 4
//      CONSECUTIVE ow for one co -> two 8B-aligned dwordx2 stores per tile.
//
// Pipeline per 4-row step: issue next step's 16 global int2v loads into regs
// -> compute current 4 rows (24 ds_read_b128 + 48 MFMA/wave) -> pack + ds_write
// to ring slots provably disjoint from any concurrently-read slots -> barrier.
// Writes (rows 4s+6..4s+9 mod 10) never alias reads (rows 4s..4s+5 mod 10).
__global__ __launch_bounds__(NTHREADS, 4) void conv_q8_ring(
    const int* __restrict__ x, const int* __restrict__ wq,
    const float* __restrict__ bias, float* __restrict__ out)
{
    __shared__ int4v lds_x[RING * COLS];  // [slot*COLS + col], 16 cin bytes/pixel
    __shared__ int4v lds_wB[192];         // [(kh*4 + kw)*16 + co]
    __shared__ int   lds_ci[COUT];        // -7*sumW + 3024
    __shared__ float lds_bf[COUT];        // dequantized bias

    const int tid   = threadIdx.x;
    const int chunk = blockIdx.x;
    const int n     = blockIdx.y;
    const int oh0   = chunk * OHC;
    const int* xn   = x + (size_t)n * (CIN * HW);

    // ---- stage packed B (weights) ----
    if (tid < 192) {
        const int co = tid & 15;
        const int kw = (tid >> 4) & 3;
        const int kh = tid >> 6;
        int4v pk = {0, 0, 0, 0};
        if (kw < 3) {
#pragma unroll
            for (int q = 0; q < 4; ++q) {
                const int* wp = wq + ((co * CIN + q * 4) * 3 + kh) * 3 + kw;
                pk[q] = pack4(wp[0], wp[9], wp[18], wp[27]);
            }
        }
        lds_wB[tid] = pk;
    }
    // ---- per-cout constants ----
    if (tid < COUT) {
        int s = 0;
        const int* wc = wq + tid * CIN * 9;
#pragma unroll
        for (int k = 0; k < CIN * 9; ++k) s += wc[k];
        lds_ci[tid] = -7 * s + 144 * 21;
        float r = rintf(bias[tid] * 10000.0f);                // round-half-even
        r = fminf(fmaxf(r, -2147483648.0f), 2147483647.0f);   // clamp int32 range
        lds_bf[tid] = r * 1e-4f;
    }
    // ---- zero halo columns 256..258 in every ring slot (never overwritten) ----
    if (tid < RING * 3) {
        const int slot = tid / 3;
        const int col  = 256 + (tid % 3);
        lds_x[slot * COLS + col] = (int4v){0, 0, 0, 0};
    }

    // ---- prologue: stage input rows oh0 .. oh0+5 ----
    for (int t = tid; t < 6 * 128; t += NTHREADS) {
        const int rloc = t >> 7;
        const int c2   = (t & 127) * 2;
        const int iru  = oh0 + rloc;
        const int ih   = (iru < H) ? iru : H - 1;
        const int* p = xn + ih * W + c2;
        int4v pk0, pk1;
#pragma unroll
        for (int q = 0; q < 4; ++q) {
            const int2v d0 = *(const int2v*)(p + (q * 4 + 0) * HW);
            const int2v d1 = *(const int2v*)(p + (q * 4 + 1) * HW);
            const int2v d2 = *(const int2v*)(p + (q * 4 + 2) * HW);
            const int2v d3 = *(const int2v*)(p + (q * 4 + 3) * HW);
            pk0[q] = pack4(d0.x, d1.x, d2.x, d3.x);
            pk1[q] = pack4(d0.y, d1.y, d2.y, d3.y);
        }
        const int slot = iru % RING;
        lds_x[slot * COLS + c2]     = pk0;
        lds_x[slot * COLS + c2 + 1] = pk1;
    }
    __syncthreads();

    const int wave = tid >> 6;
    const int lane = tid & 63;
    const int n16  = lane & 15;
    const int quad = lane >> 4;
    const int coff = n16 + quad;

    const int4v w0 = lds_wB[(0 * 4 + quad) * 16 + n16];
    const int4v w1 = lds_wB[(1 * 4 + quad) * 16 + n16];
    const int4v w2 = lds_wB[(2 * 4 + quad) * 16 + n16];
    const int ov = (quad < 3) ? 0x01010101 : 0;
    const int4v bones = {ov, ov, ov, ov};
    const int   ci_s = lds_ci[n16];
    const float bf_s = lds_bf[n16];
    const int4v zero4 = {0, 0, 0, 0};

    const int rl    = wave >> 1;        // oh row within step (0..3)
    const int gbase = (wave & 1) * 8;   // 8 ow-groups per wave
    float* outn = out + (size_t)n * (COUT * OH * OW);

    // per-thread prefetch coordinates (fixed)
    const int rloc = tid >> 7;          // 0..3
    const int c2p  = (tid & 127) * 2;

    for (int s = 0; s < STEPS; ++s) {
        // ---- (a) issue next step's global loads into registers ----
        int2v ld[16];
        const bool pf = (s < STEPS - 1);
        int slot_p = 0;
        if (pf) {
            const int iru = oh0 + 4 * s + 6 + rloc;
            slot_p = iru % RING;
            const int ih = (iru < H) ? iru : H - 1;
            const int* p = xn + ih * W + c2p;
#pragma unroll
            for (int q = 0; q < 16; ++q)
                ld[q] = *(const int2v*)(p + q * HW);
        }

        // ---- (b) compute current 4 rows ----
        const int oh  = oh0 + 4 * s + rl;
        const int sl0 = (oh    ) % RING;
        const int sl1 = (oh + 1) % RING;
        const int sl2 = (oh + 2) % RING;
        const bool do_store = (oh < OH);   // wave-uniform

#pragma unroll
        for (int gi = 0; gi < 8; ++gi) {
            const int g = gbase + gi;
            const int c = g * 16 + coff;
            const int4v p0 = lds_x[sl0 * COLS + c];
            const int4v p1 = lds_x[sl1 * COLS + c];
            const int4v p2 = lds_x[sl2 * COLS + c];
            int4v acc = __builtin_amdgcn_mfma_i32_16x16x64_i8(p0, w0, zero4, 0, 0, 0);
            acc = __builtin_amdgcn_mfma_i32_16x16x64_i8(p1, w1, acc, 0, 0, 0);
            acc = __builtin_amdgcn_mfma_i32_16x16x64_i8(p2, w2, acc, 0, 0, 0);
            int4v acs = __builtin_amdgcn_mfma_i32_16x16x64_i8(p0, bones, zero4, 0, 0, 0);
            acs = __builtin_amdgcn_mfma_i32_16x16x64_i8(p1, bones, acs, 0, 0, 0);
            acs = __builtin_amdgcn_mfma_i32_16x16x64_i8(p2, bones, acs, 0, 0, 0);
            if (do_store) {
                const int owb = g * 16 + quad * 4;
                float f0 = fmaf(1e-4f, (float)(acc[0] - 3 * acs[0] + ci_s), bf_s);
                float f1 = fmaf(1e-4f, (float)(acc[1] - 3 * acs[1] + ci_s), bf_s);
                float f2 = fmaf(1e-4f, (float)(acc[2] - 3 * acs[2] + ci_s), bf_s);
                float f3 = fmaf(1e-4f, (float)(acc[3] - 3 * acs[3] + ci_s), bf_s);
                float* ptr = outn + (n16 * OH + oh) * OW + owb;
                if (owb + 3 < OW) {           // always 8B-aligned: OW even, owb%4==0
                    *(f2v*)(ptr)     = (f2v){f0, f1};
                    *(f2v*)(ptr + 2) = (f2v){f2, f3};
                } else {                       // g==15, quad==3: ow 252..255 partial
                    if (owb + 0 < OW) ptr[0] = f0;
                    if (owb + 1 < OW) ptr[1] = f1;
                }
            }
        }

        // ---- (c) pack + commit staged rows to ring, (d) barrier ----
        if (pf) {
            int4v pk0, pk1;
#pragma unroll
            for (int q = 0; q < 4; ++q) {
                pk0[q] = pack4(ld[4 * q].x, ld[4 * q + 1].x, ld[4 * q + 2].x, ld[4 * q + 3].x);
                pk1[q] = pack4(ld[4 * q].y, ld[4 * q + 1].y, ld[4 * q + 2].y, ld[4 * q + 3].y);
            }
            lds_x[slot_p * COLS + c2p]     = pk0;
            lds_x[slot_p * COLS + c2p + 1] = pk1;
            __syncthreads();
        }
    }
}

extern "C" void kernel_launch(void* const* d_in, const int* in_sizes, int n_in,
                              void* d_out, int out_size, void* d_ws, size_t ws_size,
                              hipStream_t stream) {
    const int*   x    = (const int*)d_in[0];
    const int*   wq   = (const int*)d_in[1];
    const float* bias = (const float*)d_in[2];
    float*       out  = (float*)d_out;

    const int n = in_sizes[0] / (CIN * H * W);   // 64
    dim3 grid(SPLIT, n);
    conv_q8_ring<<<grid, NTHREADS, 0, stream>>>(x, wq, bias, out);
}